// Round 1
// baseline (5207.468 us; speedup 1.0000x reference)
//
#include <hip/hip_runtime.h>

#define N_NODES 200000
#define N_EDGES 3200000
#define F 16

__global__ __launch_bounds__(256) void scatter_kernel(
    const float* __restrict__ feat,
    const int* __restrict__ src,
    const int* __restrict__ dst,
    float* __restrict__ agg) {
    int e = blockIdx.x * blockDim.x + threadIdx.x;
    if (e >= N_EDGES) return;
    int s = src[e];
    int d = dst[e];
    const float4* fs = (const float4*)(feat + (size_t)s * F);
    float* ad = agg + (size_t)d * F;
    #pragma unroll
    for (int q = 0; q < 4; ++q) {
        float4 v = fs[q];
        atomicAdd(ad + q * 4 + 0, v.x);
        atomicAdd(ad + q * 4 + 1, v.y);
        atomicAdd(ad + q * 4 + 2, v.z);
        atomicAdd(ad + q * 4 + 3, v.w);
    }
}

template <bool RELU_OUT, bool LOGSOFTMAX>
__global__ __launch_bounds__(256) void mlp_kernel(
    const float* __restrict__ xin,
    const float* __restrict__ agg,
    const float* __restrict__ epsp,
    const float* __restrict__ wa, const float* __restrict__ ba,
    const float* __restrict__ wb, const float* __restrict__ bb,
    float* __restrict__ out) {
    __shared__ float swa[256], swb[256], sba[16], sbb[16];
    int t = threadIdx.x;
    swa[t] = wa[t];
    swb[t] = wb[t];
    if (t < 16) { sba[t] = ba[t]; sbb[t] = bb[t]; }
    __syncthreads();

    int n = blockIdx.x * blockDim.x + t;
    if (n >= N_NODES) return;

    float eps = 1.0f + *epsp;
    const float4* xr = (const float4*)(xin + (size_t)n * F);
    const float4* ar = (const float4*)(agg + (size_t)n * F);
    float h[16];
    #pragma unroll
    for (int q = 0; q < 4; ++q) {
        float4 xv = xr[q];
        float4 av = ar[q];
        h[q * 4 + 0] = eps * xv.x + av.x;
        h[q * 4 + 1] = eps * xv.y + av.y;
        h[q * 4 + 2] = eps * xv.z + av.z;
        h[q * 4 + 3] = eps * xv.w + av.w;
    }

    float m[16];
    #pragma unroll
    for (int j = 0; j < 16; ++j) {
        float acc = sba[j];
        #pragma unroll
        for (int i = 0; i < 16; ++i) acc = fmaf(h[i], swa[i * 16 + j], acc);
        m[j] = fmaxf(acc, 0.0f);
    }

    float o[16];
    #pragma unroll
    for (int j = 0; j < 16; ++j) {
        float acc = sbb[j];
        #pragma unroll
        for (int i = 0; i < 16; ++i) acc = fmaf(m[i], swb[i * 16 + j], acc);
        o[j] = RELU_OUT ? fmaxf(acc, 0.0f) : acc;
    }

    if (LOGSOFTMAX) {
        float mx = o[0];
        #pragma unroll
        for (int j = 1; j < 16; ++j) mx = fmaxf(mx, o[j]);
        float s = 0.0f;
        #pragma unroll
        for (int j = 0; j < 16; ++j) s += expf(o[j] - mx);
        float lse = mx + logf(s);
        #pragma unroll
        for (int j = 0; j < 16; ++j) o[j] -= lse;
    }

    float4* orow = (float4*)(out + (size_t)n * F);
    #pragma unroll
    for (int q = 0; q < 4; ++q) {
        orow[q] = make_float4(o[q * 4 + 0], o[q * 4 + 1], o[q * 4 + 2], o[q * 4 + 3]);
    }
}

extern "C" void kernel_launch(void* const* d_in, const int* in_sizes, int n_in,
                              void* d_out, int out_size, void* d_ws, size_t ws_size,
                              hipStream_t stream) {
    const float* x    = (const float*)d_in[0];
    const int*   ei   = (const int*)d_in[1];
    const float* eps1 = (const float*)d_in[2];
    const float* w1a  = (const float*)d_in[3];
    const float* b1a  = (const float*)d_in[4];
    const float* w1b  = (const float*)d_in[5];
    const float* b1b  = (const float*)d_in[6];
    const float* eps2 = (const float*)d_in[7];
    const float* w2a  = (const float*)d_in[8];
    const float* b2a  = (const float*)d_in[9];
    const float* w2b  = (const float*)d_in[10];
    const float* b2b  = (const float*)d_in[11];

    float* out = (float*)d_out;
    float* agg = (float*)d_ws;  // 200000*16 fp32 = 12.8 MB

    const int* src = ei;
    const int* dst = ei + N_EDGES;

    const int edge_blocks = (N_EDGES + 255) / 256;
    const int node_blocks = (N_NODES + 255) / 256;
    const size_t agg_bytes = (size_t)N_NODES * F * sizeof(float);

    // ---- Layer 1 ----
    hipMemsetAsync(agg, 0, agg_bytes, stream);
    scatter_kernel<<<edge_blocks, 256, 0, stream>>>(x, src, dst, agg);
    // h = relu(MLP1((1+eps1)*x + agg))  -> stored in d_out as scratch
    mlp_kernel<true, false><<<node_blocks, 256, 0, stream>>>(
        x, agg, eps1, w1a, b1a, w1b, b1b, out);

    // ---- Layer 2 ----
    hipMemsetAsync(agg, 0, agg_bytes, stream);
    scatter_kernel<<<edge_blocks, 256, 0, stream>>>(out, src, dst, agg);
    // out = log_softmax(MLP2((1+eps2)*h + agg))  (in-place per-row read->write)
    mlp_kernel<false, true><<<node_blocks, 256, 0, stream>>>(
        out, agg, eps2, w2a, b2a, w2b, b2b, out);
}

// Round 2
// 984.208 us; speedup vs baseline: 5.2910x; 5.2910x over previous
//
#include <hip/hip_runtime.h>

#define N_NODES 200000
#define N_EDGES 3200000
#define F 16
#define SCAN_T 1024

// ---------------- CSR build ----------------

__global__ __launch_bounds__(256) void hist_kernel(const int* __restrict__ dst,
                                                   int* __restrict__ deg) {
    int i = blockIdx.x * blockDim.x + threadIdx.x;
    int e0 = i * 4;
    if (e0 + 3 < N_EDGES) {
        int4 d = *(const int4*)(dst + e0);
        atomicAdd(&deg[d.x], 1);
        atomicAdd(&deg[d.y], 1);
        atomicAdd(&deg[d.z], 1);
        atomicAdd(&deg[d.w], 1);
    } else {
        for (int e = e0; e < N_EDGES; ++e) atomicAdd(&deg[dst[e]], 1);
    }
}

__global__ __launch_bounds__(SCAN_T) void scan_kernel(const int* __restrict__ deg,
                                                      int* __restrict__ offs,
                                                      int* __restrict__ cursor) {
    __shared__ int part[SCAN_T];
    const int t = threadIdx.x;
    const int chunk = (N_NODES + SCAN_T - 1) / SCAN_T;  // 196
    const int lo = t * chunk;
    const int hi = min(lo + chunk, N_NODES);
    int s = 0;
    for (int i = lo; i < hi; ++i) s += deg[i];
    part[t] = s;
    __syncthreads();
    // inclusive Hillis-Steele scan
    for (int off = 1; off < SCAN_T; off <<= 1) {
        int other = (t >= off) ? part[t - off] : 0;
        __syncthreads();
        part[t] += other;
        __syncthreads();
    }
    int run = part[t] - s;  // exclusive base for this chunk
    for (int i = lo; i < hi; ++i) {
        offs[i] = run;
        cursor[i] = run;
        run += deg[i];
    }
    if (t == SCAN_T - 1) offs[N_NODES] = part[SCAN_T - 1];
}

__global__ __launch_bounds__(256) void fill_kernel(const int* __restrict__ src,
                                                   const int* __restrict__ dst,
                                                   int* __restrict__ cursor,
                                                   int* __restrict__ ssrc) {
    int i = blockIdx.x * blockDim.x + threadIdx.x;
    int e0 = i * 4;
    if (e0 + 3 < N_EDGES) {
        int4 d = *(const int4*)(dst + e0);
        int4 s = *(const int4*)(src + e0);
        int p;
        p = atomicAdd(&cursor[d.x], 1); ssrc[p] = s.x;
        p = atomicAdd(&cursor[d.y], 1); ssrc[p] = s.y;
        p = atomicAdd(&cursor[d.z], 1); ssrc[p] = s.z;
        p = atomicAdd(&cursor[d.w], 1); ssrc[p] = s.w;
    } else {
        for (int e = e0; e < N_EDGES; ++e) {
            int p = atomicAdd(&cursor[dst[e]], 1);
            ssrc[p] = src[e];
        }
    }
}

// ---------------- fused gather-aggregate + MLP ----------------

template <bool RELU_OUT, bool LOGSOFTMAX>
__global__ __launch_bounds__(256) void gin_fused(
    const float* __restrict__ xin,
    const int* __restrict__ offs,
    const int* __restrict__ ssrc,
    const float* __restrict__ epsp,
    const float* __restrict__ wa, const float* __restrict__ ba,
    const float* __restrict__ wb, const float* __restrict__ bb,
    float* __restrict__ out) {
    __shared__ float swa[256], swb[256], sba[16], sbb[16];
    const int t = threadIdx.x;
    swa[t] = wa[t];
    swb[t] = wb[t];
    if (t < 16) { sba[t] = ba[t]; sbb[t] = bb[t]; }
    __syncthreads();

    const int n = blockIdx.x * blockDim.x + t;
    if (n >= N_NODES) return;

    float acc[16];
    #pragma unroll
    for (int j = 0; j < 16; ++j) acc[j] = 0.0f;

    const int beg = offs[n];
    const int end = offs[n + 1];
    int k = beg;
    for (; k + 1 < end; k += 2) {
        int s0 = ssrc[k];
        int s1 = ssrc[k + 1];
        const float4* f0 = (const float4*)(xin + (size_t)s0 * F);
        const float4* f1 = (const float4*)(xin + (size_t)s1 * F);
        float4 a0 = f0[0], a1 = f0[1], a2 = f0[2], a3 = f0[3];
        float4 b0 = f1[0], b1 = f1[1], b2 = f1[2], b3 = f1[3];
        acc[0]  += a0.x + b0.x;  acc[1]  += a0.y + b0.y;
        acc[2]  += a0.z + b0.z;  acc[3]  += a0.w + b0.w;
        acc[4]  += a1.x + b1.x;  acc[5]  += a1.y + b1.y;
        acc[6]  += a1.z + b1.z;  acc[7]  += a1.w + b1.w;
        acc[8]  += a2.x + b2.x;  acc[9]  += a2.y + b2.y;
        acc[10] += a2.z + b2.z;  acc[11] += a2.w + b2.w;
        acc[12] += a3.x + b3.x;  acc[13] += a3.y + b3.y;
        acc[14] += a3.z + b3.z;  acc[15] += a3.w + b3.w;
    }
    if (k < end) {
        int s0 = ssrc[k];
        const float4* f0 = (const float4*)(xin + (size_t)s0 * F);
        float4 a0 = f0[0], a1 = f0[1], a2 = f0[2], a3 = f0[3];
        acc[0]  += a0.x;  acc[1]  += a0.y;  acc[2]  += a0.z;  acc[3]  += a0.w;
        acc[4]  += a1.x;  acc[5]  += a1.y;  acc[6]  += a1.z;  acc[7]  += a1.w;
        acc[8]  += a2.x;  acc[9]  += a2.y;  acc[10] += a2.z;  acc[11] += a2.w;
        acc[12] += a3.x;  acc[13] += a3.y;  acc[14] += a3.z;  acc[15] += a3.w;
    }

    const float eps = 1.0f + *epsp;
    const float4* xr = (const float4*)(xin + (size_t)n * F);
    float h[16];
    #pragma unroll
    for (int q = 0; q < 4; ++q) {
        float4 xv = xr[q];
        h[q * 4 + 0] = fmaf(eps, xv.x, acc[q * 4 + 0]);
        h[q * 4 + 1] = fmaf(eps, xv.y, acc[q * 4 + 1]);
        h[q * 4 + 2] = fmaf(eps, xv.z, acc[q * 4 + 2]);
        h[q * 4 + 3] = fmaf(eps, xv.w, acc[q * 4 + 3]);
    }

    float m[16];
    #pragma unroll
    for (int j = 0; j < 16; ++j) {
        float a = sba[j];
        #pragma unroll
        for (int i = 0; i < 16; ++i) a = fmaf(h[i], swa[i * 16 + j], a);
        m[j] = fmaxf(a, 0.0f);
    }

    float o[16];
    #pragma unroll
    for (int j = 0; j < 16; ++j) {
        float a = sbb[j];
        #pragma unroll
        for (int i = 0; i < 16; ++i) a = fmaf(m[i], swb[i * 16 + j], a);
        o[j] = RELU_OUT ? fmaxf(a, 0.0f) : a;
    }

    if (LOGSOFTMAX) {
        float mx = o[0];
        #pragma unroll
        for (int j = 1; j < 16; ++j) mx = fmaxf(mx, o[j]);
        float s = 0.0f;
        #pragma unroll
        for (int j = 0; j < 16; ++j) s += expf(o[j] - mx);
        float lse = mx + logf(s);
        #pragma unroll
        for (int j = 0; j < 16; ++j) o[j] -= lse;
    }

    float4* orow = (float4*)(out + (size_t)n * F);
    #pragma unroll
    for (int q = 0; q < 4; ++q) {
        orow[q] = make_float4(o[q * 4 + 0], o[q * 4 + 1], o[q * 4 + 2], o[q * 4 + 3]);
    }
}

// ---------------- fallback (atomic scatter) kernels ----------------

__global__ __launch_bounds__(256) void scatter_kernel(
    const float* __restrict__ feat,
    const int* __restrict__ src,
    const int* __restrict__ dst,
    float* __restrict__ agg) {
    int e = blockIdx.x * blockDim.x + threadIdx.x;
    if (e >= N_EDGES) return;
    int s = src[e];
    int d = dst[e];
    const float4* fs = (const float4*)(feat + (size_t)s * F);
    float* ad = agg + (size_t)d * F;
    #pragma unroll
    for (int q = 0; q < 4; ++q) {
        float4 v = fs[q];
        atomicAdd(ad + q * 4 + 0, v.x);
        atomicAdd(ad + q * 4 + 1, v.y);
        atomicAdd(ad + q * 4 + 2, v.z);
        atomicAdd(ad + q * 4 + 3, v.w);
    }
}

template <bool RELU_OUT, bool LOGSOFTMAX>
__global__ __launch_bounds__(256) void mlp_kernel(
    const float* __restrict__ xin,
    const float* __restrict__ agg,
    const float* __restrict__ epsp,
    const float* __restrict__ wa, const float* __restrict__ ba,
    const float* __restrict__ wb, const float* __restrict__ bb,
    float* __restrict__ out) {
    __shared__ float swa[256], swb[256], sba[16], sbb[16];
    int t = threadIdx.x;
    swa[t] = wa[t];
    swb[t] = wb[t];
    if (t < 16) { sba[t] = ba[t]; sbb[t] = bb[t]; }
    __syncthreads();

    int n = blockIdx.x * blockDim.x + t;
    if (n >= N_NODES) return;

    float eps = 1.0f + *epsp;
    const float4* xr = (const float4*)(xin + (size_t)n * F);
    const float4* ar = (const float4*)(agg + (size_t)n * F);
    float h[16];
    #pragma unroll
    for (int q = 0; q < 4; ++q) {
        float4 xv = xr[q];
        float4 av = ar[q];
        h[q * 4 + 0] = fmaf(eps, xv.x, av.x);
        h[q * 4 + 1] = fmaf(eps, xv.y, av.y);
        h[q * 4 + 2] = fmaf(eps, xv.z, av.z);
        h[q * 4 + 3] = fmaf(eps, xv.w, av.w);
    }

    float m[16];
    #pragma unroll
    for (int j = 0; j < 16; ++j) {
        float a = sba[j];
        #pragma unroll
        for (int i = 0; i < 16; ++i) a = fmaf(h[i], swa[i * 16 + j], a);
        m[j] = fmaxf(a, 0.0f);
    }

    float o[16];
    #pragma unroll
    for (int j = 0; j < 16; ++j) {
        float a = sbb[j];
        #pragma unroll
        for (int i = 0; i < 16; ++i) a = fmaf(m[i], swb[i * 16 + j], a);
        o[j] = RELU_OUT ? fmaxf(a, 0.0f) : a;
    }

    if (LOGSOFTMAX) {
        float mx = o[0];
        #pragma unroll
        for (int j = 1; j < 16; ++j) mx = fmaxf(mx, o[j]);
        float s = 0.0f;
        #pragma unroll
        for (int j = 0; j < 16; ++j) s += expf(o[j] - mx);
        float lse = mx + logf(s);
        #pragma unroll
        for (int j = 0; j < 16; ++j) o[j] -= lse;
    }

    float4* orow = (float4*)(out + (size_t)n * F);
    #pragma unroll
    for (int q = 0; q < 4; ++q) {
        orow[q] = make_float4(o[q * 4 + 0], o[q * 4 + 1], o[q * 4 + 2], o[q * 4 + 3]);
    }
}

// ---------------- launch ----------------

extern "C" void kernel_launch(void* const* d_in, const int* in_sizes, int n_in,
                              void* d_out, int out_size, void* d_ws, size_t ws_size,
                              hipStream_t stream) {
    const float* x    = (const float*)d_in[0];
    const int*   ei   = (const int*)d_in[1];
    const float* eps1 = (const float*)d_in[2];
    const float* w1a  = (const float*)d_in[3];
    const float* b1a  = (const float*)d_in[4];
    const float* w1b  = (const float*)d_in[5];
    const float* b1b  = (const float*)d_in[6];
    const float* eps2 = (const float*)d_in[7];
    const float* w2a  = (const float*)d_in[8];
    const float* b2a  = (const float*)d_in[9];
    const float* w2b  = (const float*)d_in[10];
    const float* b2b  = (const float*)d_in[11];

    float* out = (float*)d_out;
    const int* src = ei;
    const int* dst = ei + N_EDGES;

    const int node_blocks = (N_NODES + 255) / 256;
    const int edge4_blocks = (N_EDGES / 4 + 255) / 256;

    // ws layout: cursor[N] | offs[N+1 pad to N+64] | ssrc[E] | h[N*F]
    size_t off_cursor = 0;
    size_t off_offs   = off_cursor + (size_t)N_NODES * 4;
    size_t off_ssrc   = off_offs + ((size_t)N_NODES + 64) * 4;
    size_t off_h      = off_ssrc + (size_t)N_EDGES * 4;
    size_t need       = off_h + (size_t)N_NODES * F * 4;

    if (ws_size >= need) {
        int*   cursor = (int*)((char*)d_ws + off_cursor);
        int*   offs   = (int*)((char*)d_ws + off_offs);
        int*   ssrc   = (int*)((char*)d_ws + off_ssrc);
        float* h      = (float*)((char*)d_ws + off_h);

        // ---- CSR build (once, reused by both layers) ----
        hipMemsetAsync(cursor, 0, (size_t)N_NODES * 4, stream);
        hist_kernel<<<edge4_blocks, 256, 0, stream>>>(dst, cursor);
        scan_kernel<<<1, SCAN_T, 0, stream>>>(cursor, offs, cursor);
        fill_kernel<<<edge4_blocks, 256, 0, stream>>>(src, dst, cursor, ssrc);

        // ---- Layer 1: h = relu(MLP1((1+eps1)*x + gather-sum)) ----
        gin_fused<true, false><<<node_blocks, 256, 0, stream>>>(
            x, offs, ssrc, eps1, w1a, b1a, w1b, b1b, h);
        // ---- Layer 2: out = log_softmax(MLP2((1+eps2)*h + gather-sum)) ----
        gin_fused<false, true><<<node_blocks, 256, 0, stream>>>(
            h, offs, ssrc, eps2, w2a, b2a, w2b, b2b, out);
    } else {
        // fallback: atomic scatter path (needs only 12.8 MB)
        float* agg = (float*)d_ws;
        const int edge_blocks = (N_EDGES + 255) / 256;
        const size_t agg_bytes = (size_t)N_NODES * F * sizeof(float);

        hipMemsetAsync(agg, 0, agg_bytes, stream);
        scatter_kernel<<<edge_blocks, 256, 0, stream>>>(x, src, dst, agg);
        mlp_kernel<true, false><<<node_blocks, 256, 0, stream>>>(
            x, agg, eps1, w1a, b1a, w1b, b1b, out);

        hipMemsetAsync(agg, 0, agg_bytes, stream);
        scatter_kernel<<<edge_blocks, 256, 0, stream>>>(out, src, dst, agg);
        mlp_kernel<false, true><<<node_blocks, 256, 0, stream>>>(
            out, agg, eps2, w2a, b2a, w2b, b2b, out);
    }
}

// Round 3
// 561.335 us; speedup vs baseline: 9.2769x; 1.7533x over previous
//
#include <hip/hip_runtime.h>

#define N_NODES 200000
#define N_EDGES 3200000
#define F 16
#define SCAN_CHUNK 1024            // elems per block in device-wide scan
#define SCAN_BLOCKS ((N_NODES + SCAN_CHUNK - 1) / SCAN_CHUNK)  // 196

// ---------------- CSR build ----------------

__global__ __launch_bounds__(256) void hist_kernel(const int* __restrict__ dst,
                                                   int* __restrict__ deg) {
    int i = blockIdx.x * blockDim.x + threadIdx.x;
    int e0 = i * 4;
    if (e0 + 3 < N_EDGES) {
        int4 d = *(const int4*)(dst + e0);
        atomicAdd(&deg[d.x], 1);
        atomicAdd(&deg[d.y], 1);
        atomicAdd(&deg[d.z], 1);
        atomicAdd(&deg[d.w], 1);
    } else {
        for (int e = e0; e < N_EDGES; ++e) atomicAdd(&deg[dst[e]], 1);
    }
}

// ---- device-wide exclusive scan over deg[N_NODES] -> offs/cursor ----
// A: per-block sums
__global__ __launch_bounds__(256) void scan_partial(const int* __restrict__ deg,
                                                    int* __restrict__ bsum) {
    __shared__ int red[256];
    const int t = threadIdx.x;
    const int i = blockIdx.x * 256 + t;          // int4 index
    int s = 0;
    if (i * 4 + 3 < N_NODES) {
        int4 v = *(const int4*)(deg + i * 4);
        s = v.x + v.y + v.z + v.w;
    } else if (i * 4 < N_NODES) {
        for (int j = i * 4; j < N_NODES; ++j) s += deg[j];
    }
    red[t] = s;
    __syncthreads();
    for (int off = 128; off > 0; off >>= 1) {
        if (t < off) red[t] += red[t + off];
        __syncthreads();
    }
    if (t == 0) bsum[blockIdx.x] = red[0];
}

// B: scan the block sums (single block)
__global__ __launch_bounds__(256) void scan_base(const int* __restrict__ bsum,
                                                 int* __restrict__ bbase,
                                                 int* __restrict__ offs) {
    __shared__ int part[256];
    const int t = threadIdx.x;
    int v = (t < SCAN_BLOCKS) ? bsum[t] : 0;
    part[t] = v;
    __syncthreads();
    for (int off = 1; off < 256; off <<= 1) {
        int other = (t >= off) ? part[t - off] : 0;
        __syncthreads();
        part[t] += other;
        __syncthreads();
    }
    if (t < SCAN_BLOCKS) bbase[t] = part[t] - v;   // exclusive
    if (t == 255) offs[N_NODES] = part[255];       // total == N_EDGES
}

// C: per-block exclusive scan + base, write offs and cursor
__global__ __launch_bounds__(256) void scan_write(const int* __restrict__ deg,
                                                  const int* __restrict__ bbase,
                                                  int* __restrict__ offs,
                                                  int* __restrict__ cursor) {
    __shared__ int part[256];
    const int t = threadIdx.x;
    const int i = blockIdx.x * 256 + t;  // int4 index
    int4 v = make_int4(0, 0, 0, 0);
    bool full = (i * 4 + 3 < N_NODES);
    if (full) v = *(const int4*)(deg + i * 4);
    int s = v.x + v.y + v.z + v.w;
    part[t] = s;
    __syncthreads();
    for (int off = 1; off < 256; off <<= 1) {
        int other = (t >= off) ? part[t - off] : 0;
        __syncthreads();
        part[t] += other;
        __syncthreads();
    }
    int run = bbase[blockIdx.x] + part[t] - s;  // exclusive prefix for elem i*4
    if (full) {
        int4 o;
        o.x = run;
        o.y = run + v.x;
        o.z = o.y + v.y;
        o.w = o.z + v.z;
        *(int4*)(offs + i * 4) = o;
        *(int4*)(cursor + i * 4) = o;
    } else if (i * 4 < N_NODES) {
        for (int j = i * 4; j < N_NODES; ++j) {
            offs[j] = run;
            cursor[j] = run;
            run += deg[j];
        }
    }
}

__global__ __launch_bounds__(256) void fill_kernel(const int* __restrict__ src,
                                                   const int* __restrict__ dst,
                                                   int* __restrict__ cursor,
                                                   int* __restrict__ ssrc) {
    int i = blockIdx.x * blockDim.x + threadIdx.x;
    int e0 = i * 4;
    if (e0 + 3 < N_EDGES) {
        int4 d = *(const int4*)(dst + e0);
        int4 s = *(const int4*)(src + e0);
        int p;
        p = atomicAdd(&cursor[d.x], 1); ssrc[p] = s.x;
        p = atomicAdd(&cursor[d.y], 1); ssrc[p] = s.y;
        p = atomicAdd(&cursor[d.z], 1); ssrc[p] = s.z;
        p = atomicAdd(&cursor[d.w], 1); ssrc[p] = s.w;
    } else {
        for (int e = e0; e < N_EDGES; ++e) {
            int p = atomicAdd(&cursor[dst[e]], 1);
            ssrc[p] = src[e];
        }
    }
}

// ---------------- fused gather-aggregate + MLP ----------------

template <bool RELU_OUT, bool LOGSOFTMAX>
__global__ __launch_bounds__(256) void gin_fused(
    const float* __restrict__ xin,
    const int* __restrict__ offs,
    const int* __restrict__ ssrc,
    const float* __restrict__ epsp,
    const float* __restrict__ wa, const float* __restrict__ ba,
    const float* __restrict__ wb, const float* __restrict__ bb,
    float* __restrict__ out) {
    __shared__ float swa[256], swb[256], sba[16], sbb[16];
    const int t = threadIdx.x;
    swa[t] = wa[t];
    swb[t] = wb[t];
    if (t < 16) { sba[t] = ba[t]; sbb[t] = bb[t]; }
    __syncthreads();

    const int n = blockIdx.x * blockDim.x + t;
    if (n >= N_NODES) return;

    float acc[16];
    #pragma unroll
    for (int j = 0; j < 16; ++j) acc[j] = 0.0f;

    const int beg = offs[n];
    const int end = offs[n + 1];
    int k = beg;
    for (; k + 1 < end; k += 2) {
        int s0 = ssrc[k];
        int s1 = ssrc[k + 1];
        const float4* f0 = (const float4*)(xin + (size_t)s0 * F);
        const float4* f1 = (const float4*)(xin + (size_t)s1 * F);
        float4 a0 = f0[0], a1 = f0[1], a2 = f0[2], a3 = f0[3];
        float4 b0 = f1[0], b1 = f1[1], b2 = f1[2], b3 = f1[3];
        acc[0]  += a0.x + b0.x;  acc[1]  += a0.y + b0.y;
        acc[2]  += a0.z + b0.z;  acc[3]  += a0.w + b0.w;
        acc[4]  += a1.x + b1.x;  acc[5]  += a1.y + b1.y;
        acc[6]  += a1.z + b1.z;  acc[7]  += a1.w + b1.w;
        acc[8]  += a2.x + b2.x;  acc[9]  += a2.y + b2.y;
        acc[10] += a2.z + b2.z;  acc[11] += a2.w + b2.w;
        acc[12] += a3.x + b3.x;  acc[13] += a3.y + b3.y;
        acc[14] += a3.z + b3.z;  acc[15] += a3.w + b3.w;
    }
    if (k < end) {
        int s0 = ssrc[k];
        const float4* f0 = (const float4*)(xin + (size_t)s0 * F);
        float4 a0 = f0[0], a1 = f0[1], a2 = f0[2], a3 = f0[3];
        acc[0]  += a0.x;  acc[1]  += a0.y;  acc[2]  += a0.z;  acc[3]  += a0.w;
        acc[4]  += a1.x;  acc[5]  += a1.y;  acc[6]  += a1.z;  acc[7]  += a1.w;
        acc[8]  += a2.x;  acc[9]  += a2.y;  acc[10] += a2.z;  acc[11] += a2.w;
        acc[12] += a3.x;  acc[13] += a3.y;  acc[14] += a3.z;  acc[15] += a3.w;
    }

    const float eps = 1.0f + *epsp;
    const float4* xr = (const float4*)(xin + (size_t)n * F);
    float h[16];
    #pragma unroll
    for (int q = 0; q < 4; ++q) {
        float4 xv = xr[q];
        h[q * 4 + 0] = fmaf(eps, xv.x, acc[q * 4 + 0]);
        h[q * 4 + 1] = fmaf(eps, xv.y, acc[q * 4 + 1]);
        h[q * 4 + 2] = fmaf(eps, xv.z, acc[q * 4 + 2]);
        h[q * 4 + 3] = fmaf(eps, xv.w, acc[q * 4 + 3]);
    }

    float m[16];
    #pragma unroll
    for (int j = 0; j < 16; ++j) {
        float a = sba[j];
        #pragma unroll
        for (int i = 0; i < 16; ++i) a = fmaf(h[i], swa[i * 16 + j], a);
        m[j] = fmaxf(a, 0.0f);
    }

    float o[16];
    #pragma unroll
    for (int j = 0; j < 16; ++j) {
        float a = sbb[j];
        #pragma unroll
        for (int i = 0; i < 16; ++i) a = fmaf(m[i], swb[i * 16 + j], a);
        o[j] = RELU_OUT ? fmaxf(a, 0.0f) : a;
    }

    if (LOGSOFTMAX) {
        float mx = o[0];
        #pragma unroll
        for (int j = 1; j < 16; ++j) mx = fmaxf(mx, o[j]);
        float s = 0.0f;
        #pragma unroll
        for (int j = 0; j < 16; ++j) s += expf(o[j] - mx);
        float lse = mx + logf(s);
        #pragma unroll
        for (int j = 0; j < 16; ++j) o[j] -= lse;
    }

    float4* orow = (float4*)(out + (size_t)n * F);
    #pragma unroll
    for (int q = 0; q < 4; ++q) {
        orow[q] = make_float4(o[q * 4 + 0], o[q * 4 + 1], o[q * 4 + 2], o[q * 4 + 3]);
    }
}

// ---------------- fallback (atomic scatter) kernels ----------------

__global__ __launch_bounds__(256) void scatter_kernel(
    const float* __restrict__ feat,
    const int* __restrict__ src,
    const int* __restrict__ dst,
    float* __restrict__ agg) {
    int e = blockIdx.x * blockDim.x + threadIdx.x;
    if (e >= N_EDGES) return;
    int s = src[e];
    int d = dst[e];
    const float4* fs = (const float4*)(feat + (size_t)s * F);
    float* ad = agg + (size_t)d * F;
    #pragma unroll
    for (int q = 0; q < 4; ++q) {
        float4 v = fs[q];
        atomicAdd(ad + q * 4 + 0, v.x);
        atomicAdd(ad + q * 4 + 1, v.y);
        atomicAdd(ad + q * 4 + 2, v.z);
        atomicAdd(ad + q * 4 + 3, v.w);
    }
}

template <bool RELU_OUT, bool LOGSOFTMAX>
__global__ __launch_bounds__(256) void mlp_kernel(
    const float* __restrict__ xin,
    const float* __restrict__ agg,
    const float* __restrict__ epsp,
    const float* __restrict__ wa, const float* __restrict__ ba,
    const float* __restrict__ wb, const float* __restrict__ bb,
    float* __restrict__ out) {
    __shared__ float swa[256], swb[256], sba[16], sbb[16];
    int t = threadIdx.x;
    swa[t] = wa[t];
    swb[t] = wb[t];
    if (t < 16) { sba[t] = ba[t]; sbb[t] = bb[t]; }
    __syncthreads();

    int n = blockIdx.x * blockDim.x + t;
    if (n >= N_NODES) return;

    float eps = 1.0f + *epsp;
    const float4* xr = (const float4*)(xin + (size_t)n * F);
    const float4* ar = (const float4*)(agg + (size_t)n * F);
    float h[16];
    #pragma unroll
    for (int q = 0; q < 4; ++q) {
        float4 xv = xr[q];
        float4 av = ar[q];
        h[q * 4 + 0] = fmaf(eps, xv.x, av.x);
        h[q * 4 + 1] = fmaf(eps, xv.y, av.y);
        h[q * 4 + 2] = fmaf(eps, xv.z, av.z);
        h[q * 4 + 3] = fmaf(eps, xv.w, av.w);
    }

    float m[16];
    #pragma unroll
    for (int j = 0; j < 16; ++j) {
        float a = sba[j];
        #pragma unroll
        for (int i = 0; i < 16; ++i) a = fmaf(h[i], swa[i * 16 + j], a);
        m[j] = fmaxf(a, 0.0f);
    }

    float o[16];
    #pragma unroll
    for (int j = 0; j < 16; ++j) {
        float a = sbb[j];
        #pragma unroll
        for (int i = 0; i < 16; ++i) a = fmaf(m[i], swb[i * 16 + j], a);
        o[j] = RELU_OUT ? fmaxf(a, 0.0f) : a;
    }

    if (LOGSOFTMAX) {
        float mx = o[0];
        #pragma unroll
        for (int j = 1; j < 16; ++j) mx = fmaxf(mx, o[j]);
        float s = 0.0f;
        #pragma unroll
        for (int j = 0; j < 16; ++j) s += expf(o[j] - mx);
        float lse = mx + logf(s);
        #pragma unroll
        for (int j = 0; j < 16; ++j) o[j] -= lse;
    }

    float4* orow = (float4*)(out + (size_t)n * F);
    #pragma unroll
    for (int q = 0; q < 4; ++q) {
        orow[q] = make_float4(o[q * 4 + 0], o[q * 4 + 1], o[q * 4 + 2], o[q * 4 + 3]);
    }
}

// ---------------- launch ----------------

extern "C" void kernel_launch(void* const* d_in, const int* in_sizes, int n_in,
                              void* d_out, int out_size, void* d_ws, size_t ws_size,
                              hipStream_t stream) {
    const float* x    = (const float*)d_in[0];
    const int*   ei   = (const int*)d_in[1];
    const float* eps1 = (const float*)d_in[2];
    const float* w1a  = (const float*)d_in[3];
    const float* b1a  = (const float*)d_in[4];
    const float* w1b  = (const float*)d_in[5];
    const float* b1b  = (const float*)d_in[6];
    const float* eps2 = (const float*)d_in[7];
    const float* w2a  = (const float*)d_in[8];
    const float* b2a  = (const float*)d_in[9];
    const float* w2b  = (const float*)d_in[10];
    const float* b2b  = (const float*)d_in[11];

    float* out = (float*)d_out;
    const int* src = ei;
    const int* dst = ei + N_EDGES;

    const int node_blocks = (N_NODES + 255) / 256;
    const int edge4_blocks = (N_EDGES / 4 + 255) / 256;

    // ws layout: deg/cursor[N] | offs[N+1 pad] | ssrc[E] | h[N*F] | bsum[256] | bbase[256]
    size_t off_cursor = 0;
    size_t off_offs   = off_cursor + (size_t)N_NODES * 4;
    size_t off_ssrc   = off_offs + ((size_t)N_NODES + 64) * 4;
    size_t off_h      = off_ssrc + (size_t)N_EDGES * 4;
    size_t off_bsum   = off_h + (size_t)N_NODES * F * 4;
    size_t off_bbase  = off_bsum + 256 * 4;
    size_t off_deg    = off_bbase + 256 * 4;
    size_t need       = off_deg + (size_t)N_NODES * 4;

    if (ws_size >= need) {
        int*   cursor = (int*)((char*)d_ws + off_cursor);
        int*   offs   = (int*)((char*)d_ws + off_offs);
        int*   ssrc   = (int*)((char*)d_ws + off_ssrc);
        float* h      = (float*)((char*)d_ws + off_h);
        int*   bsum   = (int*)((char*)d_ws + off_bsum);
        int*   bbase  = (int*)((char*)d_ws + off_bbase);
        int*   deg    = (int*)((char*)d_ws + off_deg);

        // ---- CSR build (once, reused by both layers) ----
        hipMemsetAsync(deg, 0, (size_t)N_NODES * 4, stream);
        hist_kernel<<<edge4_blocks, 256, 0, stream>>>(dst, deg);
        scan_partial<<<SCAN_BLOCKS, 256, 0, stream>>>(deg, bsum);
        scan_base<<<1, 256, 0, stream>>>(bsum, bbase, offs);
        scan_write<<<SCAN_BLOCKS, 256, 0, stream>>>(deg, bbase, offs, cursor);
        fill_kernel<<<edge4_blocks, 256, 0, stream>>>(src, dst, cursor, ssrc);

        // ---- Layer 1: h = relu(MLP1((1+eps1)*x + gather-sum)) ----
        gin_fused<true, false><<<node_blocks, 256, 0, stream>>>(
            x, offs, ssrc, eps1, w1a, b1a, w1b, b1b, h);
        // ---- Layer 2: out = log_softmax(MLP2((1+eps2)*h + gather-sum)) ----
        gin_fused<false, true><<<node_blocks, 256, 0, stream>>>(
            h, offs, ssrc, eps2, w2a, b2a, w2b, b2b, out);
    } else {
        // fallback: atomic scatter path (needs only 12.8 MB)
        float* agg = (float*)d_ws;
        const int edge_blocks = (N_EDGES + 255) / 256;
        const size_t agg_bytes = (size_t)N_NODES * F * sizeof(float);

        hipMemsetAsync(agg, 0, agg_bytes, stream);
        scatter_kernel<<<edge_blocks, 256, 0, stream>>>(x, src, dst, agg);
        mlp_kernel<true, false><<<node_blocks, 256, 0, stream>>>(
            x, agg, eps1, w1a, b1a, w1b, b1b, out);

        hipMemsetAsync(agg, 0, agg_bytes, stream);
        scatter_kernel<<<edge_blocks, 256, 0, stream>>>(out, src, dst, agg);
        mlp_kernel<false, true><<<node_blocks, 256, 0, stream>>>(
            out, agg, eps2, w2a, b2a, w2b, b2b, out);
    }
}